// Round 8
// baseline (223.854 us; speedup 1.0000x reference)
//
#include <hip/hip_runtime.h>

typedef unsigned short u16;
typedef __bf16 bf16x8 __attribute__((ext_vector_type(8)));
typedef __bf16 bf16x4 __attribute__((ext_vector_type(4)));
typedef float f32x4 __attribute__((ext_vector_type(4)));

#if __has_builtin(__builtin_amdgcn_exp2f)
#define EXP2(x) __builtin_amdgcn_exp2f(x)   // raw v_exp_f32 (inputs bounded, no denormal path)
#else
#define EXP2(x) exp2f(x)
#endif

template<int V> struct IC { static constexpr int val = V; };

// ---------- helpers ----------
__device__ __forceinline__ u16 f2bf(float f) {            // RNE fp32 -> bf16
    unsigned u = __float_as_uint(f);
    u += 0x7fffu + ((u >> 16) & 1u);
    return (u16)(u >> 16);
}

// async global->LDS, 16B per lane; LDS dest must be wave-uniform base (+lane*16 implicit)
__device__ __forceinline__ void gll16(const void* g, void* l) {
    __builtin_amdgcn_global_load_lds(
        (const __attribute__((address_space(1))) void*)g,
        (__attribute__((address_space(3))) void*)l, 16, 0, 0);
}

// ---------- fp32 -> bf16 conversion (vectorized, G13) ----------
__device__ __forceinline__ void cvt_body(const float* __restrict__ in,
                                         u16* __restrict__ out, int i) {
    float4 v = reinterpret_cast<const float4*>(in)[i];
    unsigned long long pack =
        (unsigned long long)f2bf(v.x) |
        ((unsigned long long)f2bf(v.y) << 16) |
        ((unsigned long long)f2bf(v.z) << 32) |
        ((unsigned long long)f2bf(v.w) << 48);
    reinterpret_cast<unsigned long long*>(out)[i] = pack;
}

// fused convert of the three big (B,S,H) tensors; grid covers 3*n4
__global__ __launch_bounds__(256) void cvt_bf16_3(const float* __restrict__ a,
                                                  const float* __restrict__ b,
                                                  const float* __restrict__ c,
                                                  u16* __restrict__ oa,
                                                  u16* __restrict__ ob,
                                                  u16* __restrict__ oc, int n4) {
    int i = blockIdx.x * 256 + threadIdx.x;
    if (i < n4)            cvt_body(a, oa, i);
    else if (i < 2 * n4)   cvt_body(b, ob, i - n4);
    else if (i < 3 * n4)   cvt_body(c, oc, i - 2 * n4);
}

// fused convert of the four HxH weights; grid covers 4*n4
__global__ __launch_bounds__(256) void cvt_bf16_w(const float* __restrict__ a,
                                                  const float* __restrict__ b,
                                                  const float* __restrict__ c,
                                                  const float* __restrict__ d,
                                                  u16* __restrict__ oa,
                                                  u16* __restrict__ ob,
                                                  u16* __restrict__ oc,
                                                  u16* __restrict__ od, int n4) {
    int i = blockIdx.x * 256 + threadIdx.x;
    if (i < n4)            cvt_body(a, oa, i);
    else if (i < 2 * n4)   cvt_body(b, ob, i - n4);
    else if (i < 3 * n4)   cvt_body(c, oc, i - 2 * n4);
    else if (i < 4 * n4)   cvt_body(d, od, i - 3 * n4);
}

// ---------- GEMM: C = A(M x K) @ B(N x K)^T, bf16 in, fp32 accum ----------
// (unchanged — passing since round 4)
template<int MODE>
__global__ __launch_bounds__(256) void gemm_bt(const u16* __restrict__ A,
                                               const u16* __restrict__ B,
                                               void* __restrict__ Cv,
                                               const float* __restrict__ bias) {
    constexpr int K = 1024, N = 1024;
    __shared__ __align__(16) u16 As[128 * 64];
    __shared__ __align__(16) u16 Bs[128 * 64];
    const int tid = threadIdx.x;
    const int wv = tid >> 6, lane = tid & 63, g = lane >> 4, li = lane & 15;
    const int row0 = blockIdx.y << 7, col0 = blockIdx.x << 7;
    const int wm = wv >> 1, wn = wv & 1;

    f32x4 acc[4][4] = {};

    for (int k0 = 0; k0 < K; k0 += 64) {
        __syncthreads();
#pragma unroll
        for (int i = 0; i < 4; i++) {       // A tile: 128 rows x 128B
            const int o   = (wv << 12) + (i << 10) + (lane << 4);
            const int row = o >> 7;
            const int cbg = (o & 127) ^ ((row & 7) << 4);
            gll16(A + (size_t)(row0 + row) * K + k0 + (cbg >> 1),
                  (char*)As + (wv << 12) + (i << 10));
        }
#pragma unroll
        for (int i = 0; i < 4; i++) {       // B tile (rows = output cols)
            const int o   = (wv << 12) + (i << 10) + (lane << 4);
            const int row = o >> 7;
            const int cbg = (o & 127) ^ ((row & 7) << 4);
            gll16(B + (size_t)(col0 + row) * K + k0 + (cbg >> 1),
                  (char*)Bs + (wv << 12) + (i << 10));
        }
        __syncthreads();

#pragma unroll
        for (int kk = 0; kk < 2; kk++) {
            bf16x8 af[4], bfr[4];
            const int cb = ((kk << 5) + (g << 3)) << 1;
#pragma unroll
            for (int m = 0; m < 4; m++) {
                const int row = (wm << 6) + (m << 4) + li;
                af[m] = *reinterpret_cast<const bf16x8*>(
                    (const char*)As + (row << 7) + (cb ^ ((row & 7) << 4)));
            }
#pragma unroll
            for (int n = 0; n < 4; n++) {
                const int row = (wn << 6) + (n << 4) + li;
                bfr[n] = *reinterpret_cast<const bf16x8*>(
                    (const char*)Bs + (row << 7) + (cb ^ ((row & 7) << 4)));
            }
#pragma unroll
            for (int m = 0; m < 4; m++)
#pragma unroll
                for (int n = 0; n < 4; n++)
                    acc[m][n] = __builtin_amdgcn_mfma_f32_16x16x32_bf16(
                        af[m], bfr[n], acc[m][n], 0, 0, 0);
        }
    }

    if constexpr (MODE == 0 || MODE == 3) {
        constexpr float SC = (MODE == 3) ? 0.180336880f : 1.0f;  // 1/8 * log2(e)
        u16* C = (u16*)Cv;
#pragma unroll
        for (int m = 0; m < 4; m++)
#pragma unroll
            for (int n = 0; n < 4; n++)
#pragma unroll
                for (int r = 0; r < 4; r++) {
                    int row = row0 + (wm << 6) + (m << 4) + (g << 2) + r;
                    int col = col0 + (wn << 6) + (n << 4) + li;
                    C[(size_t)row * N + col] = f2bf(acc[m][n][r] * SC);
                }
    } else if constexpr (MODE == 1) {
        float* C = (float*)Cv;
#pragma unroll
        for (int m = 0; m < 4; m++)
#pragma unroll
            for (int n = 0; n < 4; n++)
#pragma unroll
                for (int r = 0; r < 4; r++) {
                    int row = row0 + (wm << 6) + (m << 4) + (g << 2) + r;
                    int col = col0 + (wn << 6) + (n << 4) + li;
                    C[(size_t)row * N + col] = acc[m][n][r] + bias[col];
                }
    } else {  // MODE 2: V projection written per-head-transposed: (B,NH,DK,S)
        u16* C = (u16*)Cv;
#pragma unroll
        for (int m = 0; m < 4; m++)
#pragma unroll
            for (int n = 0; n < 4; n++) {
                int srow = row0 + (wm << 6) + (m << 4) + (g << 2);
                int col  = col0 + (wn << 6) + (n << 4) + li;
                int b = srow >> 11, s = srow & 2047;
                int nh = col >> 6, d = col & 63;
                unsigned long long pack =
                    (unsigned long long)f2bf(acc[m][n][0]) |
                    ((unsigned long long)f2bf(acc[m][n][1]) << 16) |
                    ((unsigned long long)f2bf(acc[m][n][2]) << 32) |
                    ((unsigned long long)f2bf(acc[m][n][3]) << 48);
                *reinterpret_cast<unsigned long long*>(
                    C + ((size_t)((b << 4) + nh) * 64 + d) * 2048 + s) = pack;
            }
    }
}

// ---------- flash attention (tau-K, in-lane P, 2 q-sets per wave) ----------
// 256 threads = 4 waves; block = (b, head, 128 q-rows); wave owns 32 q-rows as
// TWO 16-row sets (s=0: rows q0+wv*16+li, s=1: +64). K/V fragments are loaded
// once per (kk,n) and feed BOTH sets' MFMAs -> MFMA:ds_read = 2:1, staging and
// barrier cost per q-row halved vs round 7.
// LDS = 32KB: K dbuf [0,16K) (rows tau-permuted at staging), V^T dbuf [16K,32K).
// tau: LDS row pr=n*16+g*4+r holds global key g*16+n*4+r => lane (g,li) ends up
// with 16 contiguous keys g*16+{0..15}; PV A-frag packs in-lane, B-frag is one
// b128 from the naturally-ordered V^T tile. Maxless exp2 softmax (Q pre-scaled).
__global__ __launch_bounds__(256, 4) void attn_fwd(const u16* __restrict__ Q,
                                                   const u16* __restrict__ Kp,
                                                   const u16* __restrict__ Vt,
                                                   const int* __restrict__ mask,
                                                   u16* __restrict__ O) {
    constexpr int S = 2048, H = 1024;
    __shared__ __align__(16) char lds[32768];
    __shared__ int sm_bad;
    const int tid = threadIdx.x, wv = tid >> 6, lane = tid & 63;
    const int g = lane >> 4, li = lane & 15;
    const int q0 = blockIdx.x << 7, h = blockIdx.y, b = blockIdx.z;
    const char* Kg = (const char*)(Kp + (size_t)b * S * H + h * 64);
    const char* Vg = (const char*)(Vt + (size_t)(b * 16 + h) * 64 * S);

    // stage one 64-key K tile (rows tau-permuted) + V^T tile (natural key order)
    auto stageKV = [&](int bufOff, int kv2) {
#pragma unroll
        for (int i = 0; i < 2; i++) {
            const int o   = (wv << 11) + (i << 10) + (lane << 4);
            const int row = o >> 7;                        // LDS row pr = n*16+g*4+r
            const int cbg = (o & 127) ^ ((row & 7) << 4);  // pre-swizzled src col
            const int gk  = (((row >> 2) & 3) << 4) + ((row >> 4) << 2) + (row & 3);
            gll16(Kg + (size_t)(kv2 + gk) * 2048 + cbg,
                  lds + bufOff + (wv << 11) + (i << 10));
            gll16(Vg + (size_t)row * 4096 + kv2 * 2 + cbg,
                  lds + 16384 + bufOff + (wv << 11) + (i << 10));
        }
    };

    if (tid == 0) sm_bad = 0;
    stageKV(0, 0);

    // Q fragments straight from global: set s -> row q0 + s*64 + wv*16 + li
    bf16x8 qf[2][2];
#pragma unroll
    for (int s = 0; s < 2; s++) {
        const u16* Qrow = Q + (size_t)(b * S + q0 + (s << 6) + (wv << 4) + li) * H
                          + h * 64 + (g << 3);
        qf[s][0] = *reinterpret_cast<const bf16x8*>(Qrow);
        qf[s][1] = *reinterpret_cast<const bf16x8*>(Qrow + 32);
    }

    int z = 0;                                             // block mask scan, 8 keys/thread
#pragma unroll
    for (int j = 0; j < 8; j++) z |= (mask[b * S + (tid << 3) + j] == 0);
    __syncthreads();                                       // K0/V0 resident; sm_bad=0 visible
    if (z) sm_bad = 1;
    __syncthreads();
    const bool bad = (sm_bad != 0);
    int mq[2] = {1, 1};
    if (bad) {
        mq[0] = mask[b * S + q0 + (wv << 4) + li];
        mq[1] = mask[b * S + q0 + 64 + (wv << 4) + li];
    }

    // loop-invariant LDS byte offsets (within-tile; n adds a (n<<11) immediate)
    int offK[2], offV[2];
#pragma unroll
    for (int kk = 0; kk < 2; kk++) {
        offK[kk] = (li << 7) + (((kk << 6) + (g << 4)) ^ ((li & 7) << 4));  // k-dim chunk
        offV[kk] = (li << 7) + (((g << 5) + (kk << 4)) ^ ((li & 7) << 4));  // key chunk
    }

    f32x4 o_[2][4] = {};
    float l_[2] = {0.f, 0.f};

    // one 64-key tile; BUF compile-time so every LDS address is voff+imm
    auto tile = [&](auto BUF, int kv2) {
        constexpr int KOFF = decltype(BUF)::val * 8192;
        constexpr int VOFF = 16384 + decltype(BUF)::val * 8192;
        f32x4 sc[2][4] = {};
        __builtin_amdgcn_s_setprio(1);
#pragma unroll
        for (int kk = 0; kk < 2; kk++)
#pragma unroll
            for (int n = 0; n < 4; n++) {
                bf16x8 kf = *reinterpret_cast<const bf16x8*>(
                    lds + KOFF + offK[kk] + (n << 11));
                sc[0][n] = __builtin_amdgcn_mfma_f32_16x16x32_bf16(kf, qf[0][kk],
                                                                   sc[0][n], 0, 0, 0);
                sc[1][n] = __builtin_amdgcn_mfma_f32_16x16x32_bf16(kf, qf[1][kk],
                                                                   sc[1][n], 0, 0, 0);
            }
        __builtin_amdgcn_s_setprio(0);

        if (bad) {    // sc[s][n][r] is key kv2 + g*16 + n*4 + r (tau relabeling)
            const unsigned long long kb = __ballot(mask[b * S + kv2 + lane] != 0);
#pragma unroll
            for (int s = 0; s < 2; s++)
#pragma unroll
                for (int n = 0; n < 4; n++)
#pragma unroll
                    for (int r = 0; r < 4; r++) {
                        const int key = (g << 4) + (n << 2) + r;
                        const bool ok = mq[s] && ((kb >> key) & 1ull);
                        sc[s][n][r] = ok ? sc[s][n][r] : -1e9f;
                    }
        }

#pragma unroll
        for (int s = 0; s < 2; s++) {                      // maxless: p = exp2(s)
            float rs = 0.f;
#pragma unroll
            for (int n = 0; n < 4; n++)
#pragma unroll
                for (int r = 0; r < 4; r++) {
                    const float p = EXP2(sc[s][n][r]);
                    sc[s][n][r] = p;
                    rs += p;
                }
            rs += __shfl_xor(rs, 16);
            rs += __shfl_xor(rs, 32);
            l_[s] += rs;
        }

        // A-frag pack: pf[s][0] = keys g*16+{0..7}, pf[s][1] = {8..15} — in-lane
        bf16x8 pf[2][2];
#pragma unroll
        for (int s = 0; s < 2; s++)
#pragma unroll
            for (int j = 0; j < 4; j++) {
                pf[s][0][j]     = (__bf16)sc[s][0][j];
                pf[s][0][4 + j] = (__bf16)sc[s][1][j];
                pf[s][1][j]     = (__bf16)sc[s][2][j];
                pf[s][1][4 + j] = (__bf16)sc[s][3][j];
            }

        __builtin_amdgcn_s_setprio(1);
#pragma unroll
        for (int kk = 0; kk < 2; kk++)                     // O += P @ V (b128 B-frags)
#pragma unroll
            for (int n = 0; n < 4; n++) {
                bf16x8 vf = *reinterpret_cast<const bf16x8*>(
                    lds + VOFF + offV[kk] + (n << 11));
                o_[0][n] = __builtin_amdgcn_mfma_f32_16x16x32_bf16(pf[0][kk], vf,
                                                                   o_[0][n], 0, 0, 0);
                o_[1][n] = __builtin_amdgcn_mfma_f32_16x16x32_bf16(pf[1][kk], vf,
                                                                   o_[1][n], 0, 0, 0);
            }
        __builtin_amdgcn_s_setprio(0);
    };

    for (int kv = 0; kv < S; kv += 128) {
        stageKV(8192, kv + 64);            // prefetch next tile (kv+64 <= 1984 always)
        tile(IC<0>{}, kv);
        __syncthreads();                   // buf0 reads done; buf1 staging drained
        if (kv + 128 < S) stageKV(0, kv + 128);
        tile(IC<1>{}, kv + 64);
        __syncthreads();                   // buf1 reads done; buf0 staging drained
    }

    // epilogue: l of q-row g*4+r lives in lane (lane&48)+(g<<2)+r of this wave
#pragma unroll
    for (int s = 0; s < 2; s++) {
        float linv[4];
#pragma unroll
        for (int r = 0; r < 4; r++) {
            const float lr = __shfl(l_[s], (lane & 48) + (g << 2) + r);
            linv[r] = lr > 0.f ? 1.f / lr : 0.f;
        }
#pragma unroll
        for (int n = 0; n < 4; n++)
#pragma unroll
            for (int r = 0; r < 4; r++) {
                const int row = q0 + (s << 6) + (wv << 4) + (g << 2) + r;
                const int col = (h << 6) + (n << 4) + li;
                O[(size_t)(b * S + row) * H + col] = f2bf(o_[s][n][r] * linv[r]);
            }
    }
}

// ---------- launch ----------
extern "C" void kernel_launch(void* const* d_in, const int* in_sizes, int n_in,
                              void* d_out, int out_size, void* d_ws, size_t ws_size,
                              hipStream_t stream) {
    (void)in_sizes; (void)n_in; (void)out_size; (void)ws_size;
    const float* q    = (const float*)d_in[0];
    const float* k    = (const float*)d_in[1];
    const float* v    = (const float*)d_in[2];
    const int*   mask = (const int*)d_in[3];
    const float* Wq   = (const float*)d_in[4];
    const float* Wk   = (const float*)d_in[5];
    const float* Wv   = (const float*)d_in[6];
    const float* Wo   = (const float*)d_in[7];
    const float* bo   = (const float*)d_in[8];

    const size_t NEL = 8192ull * 1024ull;  // elements per (B,S,H) tensor
    u16* ws  = (u16*)d_ws;
    u16* r0  = ws;                       // q bf16  -> later K-proj
    u16* r1  = ws + NEL;                 // k bf16  -> later V^T
    u16* r2  = ws + 2 * NEL;             // v bf16  -> later attn out
    u16* wqb = ws + 3 * NEL;
    u16* wkb = wqb + 1024 * 1024;
    u16* wvb = wkb + 1024 * 1024;
    u16* wob = wvb + 1024 * 1024;
    u16* r4  = wob + 1024 * 1024;        // Q-proj (pre-scaled)

    const int n4 = (int)(NEL / 4);                 // 2,097,152 float4s per tensor
    const int cvt_blocks = (3 * n4 + 255) / 256;   // covers 3*n4
    cvt_bf16_3<<<dim3(cvt_blocks), dim3(256), 0, stream>>>(q, k, v, r0, r1, r2, n4);
    cvt_bf16_w<<<dim3(4096), dim3(256), 0, stream>>>(Wq, Wk, Wv, Wo,
                                                     wqb, wkb, wvb, wob, 262144);

    dim3 gg(8, 64), bb(256);
    gemm_bt<3><<<gg, bb, 0, stream>>>(r0, wqb, r4, nullptr);  // Q proj (scale folded)
    gemm_bt<0><<<gg, bb, 0, stream>>>(r1, wkb, r0, nullptr);  // K proj
    gemm_bt<2><<<gg, bb, 0, stream>>>(r2, wvb, r1, nullptr);  // V proj -> V^T layout

    attn_fwd<<<dim3(16, 16, 4), dim3(256), 0, stream>>>(r4, r0, r1, mask, r2);

    gemm_bt<1><<<gg, bb, 0, stream>>>(r2, wob, d_out, bo);    // out proj + bias
}

// Round 10
// 219.082 us; speedup vs baseline: 1.0218x; 1.0218x over previous
//
#include <hip/hip_runtime.h>

typedef unsigned short u16;
typedef __bf16 bf16x8 __attribute__((ext_vector_type(8)));
typedef __bf16 bf16x4 __attribute__((ext_vector_type(4)));
typedef float f32x4 __attribute__((ext_vector_type(4)));

#if __has_builtin(__builtin_amdgcn_exp2f)
#define EXP2(x) __builtin_amdgcn_exp2f(x)   // raw v_exp_f32 (inputs bounded, no denormal path)
#else
#define EXP2(x) exp2f(x)
#endif

// ---------- helpers ----------
__device__ __forceinline__ u16 f2bf(float f) {            // RNE fp32 -> bf16
    unsigned u = __float_as_uint(f);
    u += 0x7fffu + ((u >> 16) & 1u);
    return (u16)(u >> 16);
}

// async global->LDS, 16B per lane; LDS dest must be wave-uniform base (+lane*16 implicit)
__device__ __forceinline__ void gll16(const void* g, void* l) {
    __builtin_amdgcn_global_load_lds(
        (const __attribute__((address_space(1))) void*)g,
        (__attribute__((address_space(3))) void*)l, 16, 0, 0);
}

// ---------- fp32 -> bf16 conversion (vectorized, G13) ----------
__device__ __forceinline__ void cvt_body(const float* __restrict__ in,
                                         u16* __restrict__ out, int i) {
    float4 v = reinterpret_cast<const float4*>(in)[i];
    unsigned long long pack =
        (unsigned long long)f2bf(v.x) |
        ((unsigned long long)f2bf(v.y) << 16) |
        ((unsigned long long)f2bf(v.z) << 32) |
        ((unsigned long long)f2bf(v.w) << 48);
    reinterpret_cast<unsigned long long*>(out)[i] = pack;
}

// single fused convert of all 7 fp32 tensors; grid covers 3*n4 + 4*nw4
__global__ __launch_bounds__(256) void cvt_all(const float* __restrict__ q,
                                               const float* __restrict__ k,
                                               const float* __restrict__ v,
                                               const float* __restrict__ wq,
                                               const float* __restrict__ wk,
                                               const float* __restrict__ wv,
                                               const float* __restrict__ wo,
                                               u16* __restrict__ oq,
                                               u16* __restrict__ ok,
                                               u16* __restrict__ ov,
                                               u16* __restrict__ owq,
                                               u16* __restrict__ owk,
                                               u16* __restrict__ owv,
                                               u16* __restrict__ owo,
                                               int n4, int nw4) {
    int i = blockIdx.x * 256 + threadIdx.x;
    if (i < n4)          cvt_body(q, oq, i);
    else if (i < 2 * n4) cvt_body(k, ok, i - n4);
    else if (i < 3 * n4) cvt_body(v, ov, i - 2 * n4);
    else {
        int j = i - 3 * n4;
        if (j < nw4)          cvt_body(wq, owq, j);
        else if (j < 2 * nw4) cvt_body(wk, owk, j - nw4);
        else if (j < 3 * nw4) cvt_body(wv, owv, j - 2 * nw4);
        else if (j < 4 * nw4) cvt_body(wo, owo, j - 3 * nw4);
    }
}

// ---------- GEMM: C = A(M x K) @ B(N x K)^T, bf16 in, fp32 accum ----------
// (unchanged — passing since round 4)
template<int MODE>
__global__ __launch_bounds__(256) void gemm_bt(const u16* __restrict__ A,
                                               const u16* __restrict__ B,
                                               void* __restrict__ Cv,
                                               const float* __restrict__ bias) {
    constexpr int K = 1024, N = 1024;
    __shared__ __align__(16) u16 As[128 * 64];
    __shared__ __align__(16) u16 Bs[128 * 64];
    const int tid = threadIdx.x;
    const int wv = tid >> 6, lane = tid & 63, g = lane >> 4, li = lane & 15;
    const int row0 = blockIdx.y << 7, col0 = blockIdx.x << 7;
    const int wm = wv >> 1, wn = wv & 1;

    f32x4 acc[4][4] = {};

    for (int k0 = 0; k0 < K; k0 += 64) {
        __syncthreads();
#pragma unroll
        for (int i = 0; i < 4; i++) {       // A tile: 128 rows x 128B
            const int o   = (wv << 12) + (i << 10) + (lane << 4);
            const int row = o >> 7;
            const int cbg = (o & 127) ^ ((row & 7) << 4);
            gll16(A + (size_t)(row0 + row) * K + k0 + (cbg >> 1),
                  (char*)As + (wv << 12) + (i << 10));
        }
#pragma unroll
        for (int i = 0; i < 4; i++) {       // B tile (rows = output cols)
            const int o   = (wv << 12) + (i << 10) + (lane << 4);
            const int row = o >> 7;
            const int cbg = (o & 127) ^ ((row & 7) << 4);
            gll16(B + (size_t)(col0 + row) * K + k0 + (cbg >> 1),
                  (char*)Bs + (wv << 12) + (i << 10));
        }
        __syncthreads();

#pragma unroll
        for (int kk = 0; kk < 2; kk++) {
            bf16x8 af[4], bfr[4];
            const int cb = ((kk << 5) + (g << 3)) << 1;
#pragma unroll
            for (int m = 0; m < 4; m++) {
                const int row = (wm << 6) + (m << 4) + li;
                af[m] = *reinterpret_cast<const bf16x8*>(
                    (const char*)As + (row << 7) + (cb ^ ((row & 7) << 4)));
            }
#pragma unroll
            for (int n = 0; n < 4; n++) {
                const int row = (wn << 6) + (n << 4) + li;
                bfr[n] = *reinterpret_cast<const bf16x8*>(
                    (const char*)Bs + (row << 7) + (cb ^ ((row & 7) << 4)));
            }
#pragma unroll
            for (int m = 0; m < 4; m++)
#pragma unroll
                for (int n = 0; n < 4; n++)
                    acc[m][n] = __builtin_amdgcn_mfma_f32_16x16x32_bf16(
                        af[m], bfr[n], acc[m][n], 0, 0, 0);
        }
    }

    if constexpr (MODE == 0 || MODE == 3) {
        constexpr float SC = (MODE == 3) ? 0.180336880f : 1.0f;  // 1/8 * log2(e)
        u16* C = (u16*)Cv;
#pragma unroll
        for (int m = 0; m < 4; m++)
#pragma unroll
            for (int n = 0; n < 4; n++)
#pragma unroll
                for (int r = 0; r < 4; r++) {
                    int row = row0 + (wm << 6) + (m << 4) + (g << 2) + r;
                    int col = col0 + (wn << 6) + (n << 4) + li;
                    C[(size_t)row * N + col] = f2bf(acc[m][n][r] * SC);
                }
    } else if constexpr (MODE == 1) {
        float* C = (float*)Cv;
#pragma unroll
        for (int m = 0; m < 4; m++)
#pragma unroll
            for (int n = 0; n < 4; n++)
#pragma unroll
                for (int r = 0; r < 4; r++) {
                    int row = row0 + (wm << 6) + (m << 4) + (g << 2) + r;
                    int col = col0 + (wn << 6) + (n << 4) + li;
                    C[(size_t)row * N + col] = acc[m][n][r] + bias[col];
                }
    } else {  // MODE 2: V projection written per-head-transposed: (B,NH,DK,S)
        u16* C = (u16*)Cv;
#pragma unroll
        for (int m = 0; m < 4; m++)
#pragma unroll
            for (int n = 0; n < 4; n++) {
                int srow = row0 + (wm << 6) + (m << 4) + (g << 2);
                int col  = col0 + (wn << 6) + (n << 4) + li;
                int b = srow >> 11, s = srow & 2047;
                int nh = col >> 6, d = col & 63;
                unsigned long long pack =
                    (unsigned long long)f2bf(acc[m][n][0]) |
                    ((unsigned long long)f2bf(acc[m][n][1]) << 16) |
                    ((unsigned long long)f2bf(acc[m][n][2]) << 32) |
                    ((unsigned long long)f2bf(acc[m][n][3]) << 48);
                *reinterpret_cast<unsigned long long*>(
                    C + ((size_t)((b << 4) + nh) * 64 + d) * 2048 + s) = pack;
            }
    }
}

// ---------- flash attention (tau-K, in-lane P, dual-tile T15 pipeline) ----------
// 512 threads = 8 waves; block = (b, head, 128 q-rows); wave owns 16 q-rows.
// LDS 32KB: K0 @0, K1 @8K, V0 @16K, V1 @24K (tiles 64 keys x 128B, XOR-swizzled;
// K rows tau-permuted at staging so lane (g,li) gets 16 contiguous keys g*16+..).
// Pipeline (2 tiles/iter, dual score state scE/scO, all compile-time indexed):
//   QK(t+1) issue -> softmax(t) VALU runs UNDER those MFMAs -> PV(t) -> barrier
//   QK(t+2) issue -> softmax(t+1) under them              -> PV(t+1) -> barrier
// K/V staging staggered into freed buffer slots; every write-after-read hazard
// is separated by a barrier (audited per-buffer). Maxless exp2 softmax.
// ROUND-10 FIX: QK zeroes its accumulator (SM overwrites sc in place with
// exp2 probabilities; accumulating the next tile on top of them caused the
// round-9 double-exponential blow-up -> inf*0 -> NaN).
__global__ __launch_bounds__(512, 4) void attn_fwd(const u16* __restrict__ Q,
                                                   const u16* __restrict__ Kp,
                                                   const u16* __restrict__ Vt,
                                                   const int* __restrict__ mask,
                                                   u16* __restrict__ O) {
    constexpr int S = 2048, H = 1024;
    constexpr int K0OFF = 0, K1OFF = 8192, V0OFF = 16384, V1OFF = 24576;
    __shared__ __align__(16) char lds[32768];
    __shared__ int sm_bad;
    const int tid = threadIdx.x, wv = tid >> 6, lane = tid & 63;
    const int g = lane >> 4, li = lane & 15;
    const int q0 = blockIdx.x << 7, h = blockIdx.y, b = blockIdx.z;
    const char* Kg = (const char*)(Kp + (size_t)b * S * H + h * 64);
    const char* Vg = (const char*)(Vt + (size_t)(b * 16 + h) * 64 * S);

    auto stageK = [&](int koff, int kv2) {                 // rows tau-permuted
        const int o   = tid << 4;                          // 0..8191
        const int row = o >> 7;                            // LDS row pr = n*16+g*4+r
        const int cbg = (o & 127) ^ ((row & 7) << 4);      // pre-swizzled src col
        const int gk  = (((row >> 2) & 3) << 4) + ((row >> 4) << 2) + (row & 3);
        gll16(Kg + (size_t)(kv2 + gk) * 2048 + cbg, lds + koff + (wv << 10));
    };
    auto stageV = [&](int voff, int kv2) {                 // natural key order
        const int o   = tid << 4;
        const int row = o >> 7;
        const int cbg = (o & 127) ^ ((row & 7) << 4);
        gll16(Vg + (size_t)row * 4096 + kv2 * 2 + cbg, lds + voff + (wv << 10));
    };

    if (tid == 0) sm_bad = 0;
    stageK(K0OFF, 0);
    stageV(V0OFF, 0);
    stageK(K1OFF, 64);

    // Q fragments straight from global: lane (g,li) = row q0+wv*16+li, dims g*8+kk*32..
    bf16x8 qf[2];
    {
        const u16* Qrow = Q + (size_t)(b * S + q0 + (wv << 4) + li) * H + h * 64 + (g << 3);
        qf[0] = *reinterpret_cast<const bf16x8*>(Qrow);
        qf[1] = *reinterpret_cast<const bf16x8*>(Qrow + 32);
    }

    int z = 0;                                             // block mask scan, 4 keys/thread
#pragma unroll
    for (int j = 0; j < 4; j++) z |= (mask[b * S + (tid << 2) + j] == 0);
    __syncthreads();                                       // K0/V0/K1 resident; sm_bad=0 seen
    if (z) sm_bad = 1;

    // loop-invariant LDS byte offsets (within-tile; n adds a (n<<11) immediate)
    int offK[2], offV[2];
#pragma unroll
    for (int kk = 0; kk < 2; kk++) {
        offK[kk] = (li << 7) + (((kk << 6) + (g << 4)) ^ ((li & 7) << 4));  // k-dim chunk
        offV[kk] = (li << 7) + (((g << 5) + (kk << 4)) ^ ((li & 7) << 4));  // key chunk
    }

    f32x4 scE[4] = {}, scO[4] = {};
    auto QK = [&](int koff, f32x4 (&sc)[4]) {
#pragma unroll
        for (int n = 0; n < 4; n++) sc[n] = f32x4{};       // fresh accumulator (r10 fix)
        __builtin_amdgcn_s_setprio(1);
#pragma unroll
        for (int kk = 0; kk < 2; kk++)
#pragma unroll
            for (int n = 0; n < 4; n++) {
                bf16x8 kf = *reinterpret_cast<const bf16x8*>(
                    lds + koff + offK[kk] + (n << 11));
                sc[n] = __builtin_amdgcn_mfma_f32_16x16x32_bf16(kf, qf[kk], sc[n], 0, 0, 0);
            }
        __builtin_amdgcn_s_setprio(0);
    };

    QK(K0OFF, scE);                                        // S(0)
    __syncthreads();                                       // all S(0) reads done; sm_bad seen
    const bool bad = (sm_bad != 0);
    const int  mq  = bad ? mask[b * S + q0 + (wv << 4) + li] : 1;

    f32x4 o_[4] = {};
    float l_ = 0.f;
    bf16x8 pfE[2], pfO[2];

    auto SM = [&](f32x4 (&sc)[4], bf16x8 (&pf)[2], int kv2) {
        if (bad) {    // sc[n][r] is key kv2 + g*16 + n*4 + r (tau relabeling)
            const unsigned long long kb = __ballot(mask[b * S + kv2 + lane] != 0);
#pragma unroll
            for (int n = 0; n < 4; n++)
#pragma unroll
                for (int r = 0; r < 4; r++) {
                    const int key = (g << 4) + (n << 2) + r;
                    const bool ok = mq && ((kb >> key) & 1ull);
                    sc[n][r] = ok ? sc[n][r] : -1e9f;
                }
        }
        float rs = 0.f;                                    // maxless: p = exp2(s)
#pragma unroll
        for (int n = 0; n < 4; n++)
#pragma unroll
            for (int r = 0; r < 4; r++) {
                const float p = EXP2(sc[n][r]);
                sc[n][r] = p;
                rs += p;
            }
        rs += __shfl_xor(rs, 16);
        rs += __shfl_xor(rs, 32);
        l_ += rs;
#pragma unroll
        for (int j = 0; j < 4; j++) {                      // in-lane A-frag pack
            pf[0][j]     = (__bf16)sc[0][j];
            pf[0][4 + j] = (__bf16)sc[1][j];
            pf[1][j]     = (__bf16)sc[2][j];
            pf[1][4 + j] = (__bf16)sc[3][j];
        }
    };

    auto PV = [&](int voff, bf16x8 (&pf)[2]) {
        __builtin_amdgcn_s_setprio(1);
#pragma unroll
        for (int kk = 0; kk < 2; kk++)
#pragma unroll
            for (int n = 0; n < 4; n++) {
                bf16x8 vf = *reinterpret_cast<const bf16x8*>(
                    lds + voff + offV[kk] + (n << 11));
                o_[n] = __builtin_amdgcn_mfma_f32_16x16x32_bf16(pf[kk], vf, o_[n], 0, 0, 0);
            }
        __builtin_amdgcn_s_setprio(0);
    };

    for (int kv = 0; kv < S; kv += 128) {
        stageV(V1OFF, kv + 64);                 // A: V(t+1); V1 freed pre-prev-barrier
        QK(K1OFF, scO);                         // B: S(t+1) reads K1 (staged, drained)
        if (kv + 128 < S) stageK(K0OFF, kv + 128);  // C: K0 freed by S(t) pre-barrier
        SM(scE, pfE, kv);                       // D: softmax(t) under B's MFMAs
        PV(V0OFF, pfE);                         // E: PV(t) reads V0
        __syncthreads();                        // F: A,C drained; V0,K1 readers done
        if (kv + 128 < S) {
            stageV(V0OFF, kv + 128);            // G: V0 freed by E (barrier F)
            QK(K0OFF, scE);                     // H: S(t+2) reads K0 (C, drained at F)
        }
        if (kv + 192 < S) stageK(K1OFF, kv + 192);  // I: K1 freed by B (barrier F)
        SM(scO, pfO, kv + 64);                  // J: softmax(t+1) under H's MFMAs
        PV(V1OFF, pfO);                         // K: PV(t+1) reads V1 (A, drained at F)
        __syncthreads();                        // L: G,I drained; V1,K0 readers done
    }

    // epilogue: l of q-row g*4+r lives in lane (lane&48)+(g<<2)+r of this wave
    float linv[4];
#pragma unroll
    for (int r = 0; r < 4; r++) {
        const float lr = __shfl(l_, (lane & 48) + (g << 2) + r);
        linv[r] = lr > 0.f ? 1.f / lr : 0.f;
    }
#pragma unroll
    for (int n = 0; n < 4; n++)
#pragma unroll
        for (int r = 0; r < 4; r++) {
            const int row = q0 + (wv << 4) + (g << 2) + r;
            const int col = (h << 6) + (n << 4) + li;
            O[(size_t)(b * S + row) * H + col] = f2bf(o_[n][r] * linv[r]);
        }
}

// ---------- launch ----------
extern "C" void kernel_launch(void* const* d_in, const int* in_sizes, int n_in,
                              void* d_out, int out_size, void* d_ws, size_t ws_size,
                              hipStream_t stream) {
    (void)in_sizes; (void)n_in; (void)out_size; (void)ws_size;
    const float* q    = (const float*)d_in[0];
    const float* k    = (const float*)d_in[1];
    const float* v    = (const float*)d_in[2];
    const int*   mask = (const int*)d_in[3];
    const float* Wq   = (const float*)d_in[4];
    const float* Wk   = (const float*)d_in[5];
    const float* Wv   = (const float*)d_in[6];
    const float* Wo   = (const float*)d_in[7];
    const float* bo   = (const float*)d_in[8];

    const size_t NEL = 8192ull * 1024ull;  // elements per (B,S,H) tensor
    u16* ws  = (u16*)d_ws;
    u16* r0  = ws;                       // q bf16  -> later K-proj
    u16* r1  = ws + NEL;                 // k bf16  -> later V^T
    u16* r2  = ws + 2 * NEL;             // v bf16  -> later attn out
    u16* wqb = ws + 3 * NEL;
    u16* wkb = wqb + 1024 * 1024;
    u16* wvb = wkb + 1024 * 1024;
    u16* wob = wvb + 1024 * 1024;
    u16* r4  = wob + 1024 * 1024;        // Q-proj (pre-scaled)

    const int n4  = (int)(NEL / 4);                // 2,097,152 float4s per big tensor
    const int nw4 = 262144;                        // float4s per HxH weight
    const int cvt_blocks = (3 * n4 + 4 * nw4 + 255) / 256;   // covers all 7 tensors
    cvt_all<<<dim3(cvt_blocks), dim3(256), 0, stream>>>(
        q, k, v, Wq, Wk, Wv, Wo, r0, r1, r2, wqb, wkb, wvb, wob, n4, nw4);

    dim3 gg(8, 64), bb(256);
    gemm_bt<3><<<gg, bb, 0, stream>>>(r0, wqb, r4, nullptr);  // Q proj (scale folded)
    gemm_bt<0><<<gg, bb, 0, stream>>>(r1, wkb, r0, nullptr);  // K proj
    gemm_bt<2><<<gg, bb, 0, stream>>>(r2, wvb, r1, nullptr);  // V proj -> V^T layout

    attn_fwd<<<dim3(16, 16, 4), dim3(512), 0, stream>>>(r4, r0, r1, mask, r2);

    gemm_bt<1><<<gg, bb, 0, stream>>>(r2, wob, d_out, bo);    // out proj + bias
}